// Round 3
// baseline (735.020 us; speedup 1.0000x reference)
//
#include <hip/hip_runtime.h>

typedef __bf16 bf16;
typedef __attribute__((ext_vector_type(8))) __bf16 bf16x8;
typedef __attribute__((ext_vector_type(4))) __bf16 bf16x4;
typedef __attribute__((ext_vector_type(4))) float f32x4;

// ---------------- matvec (wave per row) + optional ReLU/mask ----------------
__global__ __launch_bounds__(256) void mv_relu(const float* __restrict__ W,
    const float* __restrict__ v, float* __restrict__ h, float* __restrict__ m,
    float* __restrict__ z, int K) {
  const int row  = (blockIdx.x * blockDim.x + threadIdx.x) >> 6;
  const int lane = threadIdx.x & 63;
  const float* wr = W + (size_t)row * K;
  float s = 0.f;
  for (int c = lane * 4; c < K; c += 256) {
    const float4 w4 = *(const float4*)(wr + c);
    const float4 v4 = *(const float4*)(v + c);
    s += w4.x * v4.x + w4.y * v4.y + w4.z * v4.z + w4.w * v4.w;
  }
  #pragma unroll
  for (int off = 32; off; off >>= 1) s += __shfl_xor(s, off);
  if (lane == 0) {
    if (h) { h[row] = s > 0.f ? s : 0.f; m[row] = s > 0.f ? 1.f : 0.f; }
    if (z) z[row] = s;
  }
}

// ---------------- 32x32 LDS-tiled transpose: f32 out + optional scaled bf16 out
__global__ __launch_bounds__(256) void transpose_k(const float* __restrict__ in,
    float* __restrict__ outT, bf16* __restrict__ outT_bf,
    const float* __restrict__ scale, int R, int C) {
  __shared__ float tile[32][33];
  const int tr = blockIdx.y * 32, tc = blockIdx.x * 32;
  const int tx = threadIdx.x, ty = threadIdx.y;   // block (32,8)
  #pragma unroll
  for (int s = 0; s < 4; ++s)
    tile[ty + s * 8][tx] = in[(size_t)(tr + ty + s * 8) * C + (tc + tx)];
  __syncthreads();
  const float sc = scale ? scale[tr + tx] : 1.f;
  #pragma unroll
  for (int s = 0; s < 4; ++s) {
    const int oc = ty + s * 8;
    const float v = tile[tx][oc];
    const size_t o = (size_t)(tc + oc) * R + (tr + tx);
    outT[o] = v;
    if (outT_bf) outT_bf[o] = (bf16)(v * sc);
  }
}

// ---------------- diagonal matrix fill: out[n][n] = diag(d) (d==null -> I) ----
__global__ __launch_bounds__(256) void diag_fill(float* __restrict__ out,
    const float* __restrict__ d, int n) {
  const size_t i = ((size_t)blockIdx.x * blockDim.x + threadIdx.x) * 4;
  const int row = (int)(i >> (31 - __clz(n)));     // i / n  (n power of 2)
  const int c0  = (int)(i & (size_t)(n - 1));
  float4 v = make_float4(0.f, 0.f, 0.f, 0.f);
  const int dpos = row - c0;
  if ((unsigned)dpos < 4u) ((float*)&v)[dpos] = d ? d[row] : 1.f;
  *(float4*)(out + i) = v;
}

// ---------------- out[r][c]=bf16(in[r][c]*s[c]) ------------------------------
__global__ __launch_bounds__(256) void scale_cols_bf(const float* __restrict__ in,
    const float* __restrict__ scale, bf16* __restrict__ out, int cmask) {
  const size_t i = ((size_t)blockIdx.x * blockDim.x + threadIdx.x) * 4;
  const float4 v = *(const float4*)(in + i);
  const int c = (int)(i & (size_t)cmask);
  const float4 s4 = *(const float4*)(scale + c);
  bf16x4 o;
  o[0] = (bf16)(v.x * s4.x); o[1] = (bf16)(v.y * s4.y);
  o[2] = (bf16)(v.z * s4.z); o[3] = (bf16)(v.w * s4.w);
  *(bf16x4*)(out + i) = o;
}

// ---------------- split-K reduces -------------------------------------------
__global__ __launch_bounds__(256) void reduce2_bf(const float* __restrict__ P,
    bf16* __restrict__ out, size_t L) {
  const size_t i = ((size_t)blockIdx.x * blockDim.x + threadIdx.x) * 4;
  const float4 a = *(const float4*)(P + i);
  const float4 b = *(const float4*)(P + L + i);
  bf16x4 o;
  o[0] = (bf16)(a.x + b.x); o[1] = (bf16)(a.y + b.y);
  o[2] = (bf16)(a.z + b.z); o[3] = (bf16)(a.w + b.w);
  *(bf16x4*)(out + i) = o;
}

__global__ __launch_bounds__(256) void reduce4_f32(const float* __restrict__ P,
    float* __restrict__ out, size_t L) {
  const size_t i = ((size_t)blockIdx.x * blockDim.x + threadIdx.x) * 4;
  const float4 a = *(const float4*)(P + i);
  const float4 b = *(const float4*)(P + L + i);
  const float4 c = *(const float4*)(P + 2 * L + i);
  const float4 d = *(const float4*)(P + 3 * L + i);
  float4 o;
  o.x = (a.x + b.x) + (c.x + d.x);
  o.y = (a.y + b.y) + (c.y + d.y);
  o.z = (a.z + b.z) + (c.z + d.z);
  o.w = (a.w + b.w) + (c.w + d.w);
  *(float4*)(out + i) = o;
}

// ---------------- bf16 NT GEMM, m97 structure, split-K -----------------------
// P[z][M][N] partial = A[M][kz..kz+Ks] @ B[N][kz..kz+Ks]^T
__device__ inline void load_lds16(const bf16* g, bf16* lds) {
  __builtin_amdgcn_global_load_lds(
      (const __attribute__((address_space(1))) void*)g,
      (__attribute__((address_space(3))) void*)lds, 16, 0, 0);
}

__global__ __launch_bounds__(256) void gemm_nt_sk(const bf16* __restrict__ A,
    const bf16* __restrict__ B, float* __restrict__ P, int M, int N, int K,
    int Ks) {
  constexpr int BM = 128, BN = 128, BK = 32;
  __shared__ __align__(16) bf16 As[BM * BK];
  __shared__ __align__(16) bf16 Bs[BN * BK];
  const int tid = threadIdx.x, lane = tid & 63, wave = tid >> 6;
  const int wm = wave >> 1, wn = wave & 1;            // 2x2 waves, 64x64 each
  const int tm = blockIdx.y, tn = blockIdx.x;
  const int kt0 = blockIdx.z * Ks;

  f32x4 acc[4][4] = {};

  const int ldrow = lane >> 2;          // row within 16-row staging chunk
  const int ldk   = (lane & 3) * 8;     // k offset (bf16 elements)
  const long arow0 = (long)(tm * BM) * K;
  const long brow0 = (long)(tn * BN) * K;

  for (int kt = kt0; kt < kt0 + Ks; kt += BK) {
    #pragma unroll
    for (int s = 0; s < 2; ++s) {
      const int chunk = wave * 2 + s;                 // 8 chunks of 16 rows
      const int row = chunk * 16 + ldrow;
      load_lds16(A + arow0 + (long)row * K + kt + ldk, As + chunk * 512);
      load_lds16(B + brow0 + (long)row * K + kt + ldk, Bs + chunk * 512);
    }
    __syncthreads();
    bf16x8 af[4], bfr[4];
    const int ko = (lane >> 4) * 8;
    const int fr = lane & 15;
    #pragma unroll
    for (int f = 0; f < 4; ++f) {
      af[f]  = *(const bf16x8*)(As + (wm * 64 + f * 16 + fr) * BK + ko);
      bfr[f] = *(const bf16x8*)(Bs + (wn * 64 + f * 16 + fr) * BK + ko);
    }
    #pragma unroll
    for (int mf = 0; mf < 4; ++mf)
      #pragma unroll
      for (int nf = 0; nf < 4; ++nf)
        acc[mf][nf] = __builtin_amdgcn_mfma_f32_16x16x32_bf16(
            af[mf], bfr[nf], acc[mf][nf], 0, 0, 0);
    __syncthreads();
  }

  // epilogue: C/D layout col=lane&15, row=(lane>>4)*4+reg (m89/m91 verified)
  float* Pz = P + (size_t)blockIdx.z * M * N;
  const int cr = (lane >> 4) * 4;
  const int cc = lane & 15;
  #pragma unroll
  for (int mf = 0; mf < 4; ++mf) {
    const int r0 = tm * BM + wm * 64 + mf * 16 + cr;
    #pragma unroll
    for (int nf = 0; nf < 4; ++nf) {
      const long c0 = (long)r0 * N + tn * BN + wn * 64 + nf * 16 + cc;
      #pragma unroll
      for (int r = 0; r < 4; ++r)
        Pz[c0 + (long)r * N] = acc[mf][nf][r];
    }
  }
}

// ---------------------------------------------------------------------------
extern "C" void kernel_launch(void* const* d_in, const int* in_sizes, int n_in,
                              void* d_out, int out_size, void* d_ws, size_t ws_size,
                              hipStream_t stream) {
  const float* x  = (const float*)d_in[0];
  const float* W1 = (const float*)d_in[1];   // [4096][2048]
  const float* W2 = (const float*)d_in[2];   // [4096][4096]
  const float* W3 = (const float*)d_in[3];   // [2048][4096]
  float* out = (float*)d_out;
  constexpr int IN = 2048, HS = 4096, ON = 2048;

  // output layout (flat concat in return order)
  float* z3   = out;                            // [1][2048]
  float* DJM  = z3 + IN;                        // [2048][2048]  (i,o)
  float* jac0 = DJM + (size_t)IN * ON;          // W1^T [2048][4096]
  float* jac1 = jac0 + (size_t)IN * HS;         // diag(m1) [4096][4096]
  float* jac2 = jac1 + (size_t)HS * HS;         // W2^T [4096][4096]
  float* jac3 = jac2 + (size_t)HS * HS;         // diag(m2) [4096][4096]
  float* jac4 = jac3 + (size_t)HS * HS;         // W3^T [4096][2048]
  float* jac5 = jac4 + (size_t)HS * ON;         // eye [2048][2048]

  // workspace (≈145 MB)
  char* ws = (char*)d_ws;
  float* h1 = (float*)ws;                       // [4096]
  float* m1 = h1 + HS;
  float* h2 = m1 + HS;
  float* m2 = h2 + HS;
  size_t off = 1 << 20;
  bf16* W1Ts = (bf16*)(ws + off); off += (size_t)IN * HS * 2;  // bf16(W1^T·m1col)
  bf16* W2T  = (bf16*)(ws + off); off += (size_t)HS * HS * 2;  // bf16(W2^T)
  bf16* W3s  = (bf16*)(ws + off); off += (size_t)ON * HS * 2;  // bf16(W3·m2col)
  bf16* T1   = (bf16*)(ws + off); off += (size_t)ON * HS * 2;  // [2048][4096]
  float* P   = (float*)(ws + off);                             // 64 MB, time-shared

  // 1) forward matvecs (f32 exact)
  mv_relu<<<HS * 64 / 256, 256, 0, stream>>>(W1, x,  h1, m1, nullptr, IN);
  mv_relu<<<HS * 64 / 256, 256, 0, stream>>>(W2, h1, h2, m2, nullptr, HS);
  mv_relu<<<ON * 64 / 256, 256, 0, stream>>>(W3, h2, nullptr, nullptr, z3, HS);

  // 2) transposes: f32 jac outputs + bf16 GEMM operands in one pass
  dim3 tb(32, 8);
  transpose_k<<<dim3(IN / 32, HS / 32), tb, 0, stream>>>(W1, jac0, W1Ts, m1, HS, IN);
  transpose_k<<<dim3(HS / 32, HS / 32), tb, 0, stream>>>(W2, jac2, W2T, nullptr, HS, HS);
  transpose_k<<<dim3(HS / 32, ON / 32), tb, 0, stream>>>(W3, jac4, nullptr, nullptr, ON, HS);

  // 3) A-operand of GEMM1: bf16(W3 * m2 per column)
  scale_cols_bf<<<(ON * HS / 4) / 256, 256, 0, stream>>>(W3, m2, W3s, HS - 1);

  // 4) diagonal jacobians + identity
  diag_fill<<<((size_t)HS * HS / 4) / 256, 256, 0, stream>>>(jac1, m1, HS);
  diag_fill<<<((size_t)HS * HS / 4) / 256, 256, 0, stream>>>(jac3, m2, HS);
  diag_fill<<<((size_t)ON * ON / 4) / 256, 256, 0, stream>>>(jac5, nullptr, ON);

  // 5) DJM = (W1^T D1) (W2^T D2 W3^T) as two split-K NT GEMMs (grid=1024 each):
  //    T1[o][j] = sum_k W3s[o][k] * W2T[j][k]   (M=2048,N=4096,K=4096, split 2)
  gemm_nt_sk<<<dim3(HS / 128, ON / 128, 2), 256, 0, stream>>>(W3s, W2T, P, ON, HS, HS, HS / 2);
  reduce2_bf<<<((size_t)ON * HS / 4) / 256, 256, 0, stream>>>(P, T1, (size_t)ON * HS);
  //    DJM[i][o] = sum_j W1Ts[i][j] * T1[o][j]  (M=2048,N=2048,K=4096, split 4)
  gemm_nt_sk<<<dim3(ON / 128, IN / 128, 4), 256, 0, stream>>>(W1Ts, T1, P, IN, ON, HS, HS / 4);
  reduce4_f32<<<((size_t)IN * ON / 4) / 256, 256, 0, stream>>>(P, DJM, (size_t)IN * ON);
}

// Round 4
// 642.736 us; speedup vs baseline: 1.1436x; 1.1436x over previous
//
#include <hip/hip_runtime.h>

typedef __bf16 bf16;
typedef __attribute__((ext_vector_type(8))) __bf16 bf16x8;
typedef __attribute__((ext_vector_type(4))) __bf16 bf16x4;
typedef __attribute__((ext_vector_type(4))) float f32x4;

// meta layout: [0]=Sj (Nc1 rounded to 128), [1]=Sk (Nc2 rounded to 32),
//              [2]=2048 (const N for GEMM2), [3]=Sj (K for GEMM2),
//              [4]=Nc1, [5]=Nc2

// ---------------- matvec (wave per row) + optional ReLU/mask ----------------
__global__ __launch_bounds__(256) void mv_relu(const float* __restrict__ W,
    const float* __restrict__ v, float* __restrict__ h, float* __restrict__ m,
    float* __restrict__ z, int K) {
  const int row  = (blockIdx.x * blockDim.x + threadIdx.x) >> 6;
  const int lane = threadIdx.x & 63;
  const float* wr = W + (size_t)row * K;
  float s = 0.f;
  for (int c = lane * 4; c < K; c += 256) {
    const float4 w4 = *(const float4*)(wr + c);
    const float4 v4 = *(const float4*)(v + c);
    s += w4.x * v4.x + w4.y * v4.y + w4.z * v4.z + w4.w * v4.w;
  }
  #pragma unroll
  for (int off = 32; off; off >>= 1) s += __shfl_xor(s, off);
  if (lane == 0) {
    if (h) { h[row] = s > 0.f ? s : 0.f; m[row] = s > 0.f ? 1.f : 0.f; }
    if (z) z[row] = s;
  }
}

// ---------------- mask scan: inverse index lists + padded sizes --------------
__global__ __launch_bounds__(1024) void scan_meta(const float* __restrict__ m1,
    const float* __restrict__ m2, int* __restrict__ meta,
    int* __restrict__ inv1, int* __restrict__ inv2) {
  __shared__ int sd[1024];
  const int t = threadIdx.x;
  #pragma unroll
  for (int pass = 0; pass < 2; ++pass) {
    const float* m = pass ? m2 : m1;
    int* inv = pass ? inv2 : inv1;
    const float4 v = *(const float4*)(m + t * 4);
    const int f0 = v.x > 0.f, f1 = v.y > 0.f, f2 = v.z > 0.f, f3 = v.w > 0.f;
    const int ls = f0 + f1 + f2 + f3;
    sd[t] = ls;
    __syncthreads();
    for (int off = 1; off < 1024; off <<= 1) {
      const int a = sd[t];
      const int b = (t >= off) ? sd[t - off] : 0;
      __syncthreads();
      sd[t] = a + b;
      __syncthreads();
    }
    int p = sd[t] - ls;                 // exclusive prefix
    const int total = sd[1023];
    if (f0) inv[p++] = t * 4 + 0;
    if (f1) inv[p++] = t * 4 + 1;
    if (f2) inv[p++] = t * 4 + 2;
    if (f3) inv[p++] = t * 4 + 3;
    if (t == 0) {
      if (!pass) { const int Sj = (total + 127) & ~127; meta[0] = Sj; meta[3] = Sj; meta[4] = total; }
      else       { const int Sk = (total + 31) & ~31;   meta[1] = Sk; meta[5] = total; }
    }
    __syncthreads();
  }
  if (t == 0) meta[2] = 2048;
}

// ---------------- float4-vectorized 32x32 tiled transpose -------------------
__global__ __launch_bounds__(256) void transpose_f32(const float* __restrict__ in,
    float* __restrict__ outT, int R, int C) {
  __shared__ float tile[32][33];
  const int tr = blockIdx.y * 32, tc = blockIdx.x * 32;
  const int tid = threadIdx.x;
  const int lr = tid >> 3, lc4 = (tid & 7) * 4;
  const float4 v = *(const float4*)(in + (size_t)(tr + lr) * C + tc + lc4);
  tile[lr][lc4] = v.x; tile[lr][lc4 + 1] = v.y;
  tile[lr][lc4 + 2] = v.z; tile[lr][lc4 + 3] = v.w;
  __syncthreads();
  const int oc = tid & 31, or4 = (tid >> 5) * 4;
  float4 w;
  w.x = tile[or4 + 0][oc]; w.y = tile[or4 + 1][oc];
  w.z = tile[or4 + 2][oc]; w.w = tile[or4 + 3][oc];
  *(float4*)(outT + (size_t)(tc + oc) * R + tr + or4) = w;
}

// ---------------- diagonal matrix fill: out[n][n] = diag(d) (d==null -> I) ---
__global__ __launch_bounds__(256) void diag_fill(float* __restrict__ out,
    const float* __restrict__ d, int n) {
  const size_t i = ((size_t)blockIdx.x * blockDim.x + threadIdx.x) * 4;
  const int row = (int)(i >> (31 - __clz(n)));     // i / n  (n power of 2)
  const int c0  = (int)(i & (size_t)(n - 1));
  float4 v = make_float4(0.f, 0.f, 0.f, 0.f);
  const int dpos = row - c0;
  if ((unsigned)dpos < 4u) ((float*)&v)[dpos] = d ? d[row] : 1.f;
  *(float4*)(out + i) = v;
}

// ---------------- compaction gathers (f32 -> bf16, zero-padded) -------------
// W1c[i][jc] = jac0[i][inv1[jc]]  (jc<Nc1 else 0), row stride Sj
__global__ __launch_bounds__(256) void g_W1c(const float* __restrict__ jac0,
    const int* __restrict__ inv1, const int* __restrict__ meta,
    bf16* __restrict__ dst) {
  const int Sj = meta[0], Nc1 = meta[4];
  const int jc0 = blockIdx.x * 1024 + threadIdx.x * 4;
  if (jc0 >= Sj) return;
  const float* row = jac0 + (size_t)blockIdx.y * 4096;
  bf16x4 o;
  #pragma unroll
  for (int e = 0; e < 4; ++e)
    o[e] = (jc0 + e < Nc1) ? (bf16)row[inv1[jc0 + e]] : (bf16)0.f;
  *(bf16x4*)(dst + (size_t)blockIdx.y * Sj + jc0) = o;
}

// W2c[jc][kc] = jac2[inv1[jc]][inv2[kc]]  (zero-padded rows/cols), stride Sk
__global__ __launch_bounds__(256) void g_W2c(const float* __restrict__ jac2,
    const int* __restrict__ inv1, const int* __restrict__ inv2,
    const int* __restrict__ meta, bf16* __restrict__ dst) {
  const int Sj = meta[0], Sk = meta[1], Nc1 = meta[4], Nc2 = meta[5];
  const int jc = blockIdx.y;
  if (jc >= Sj) return;
  const int kc0 = blockIdx.x * 1024 + threadIdx.x * 4;
  if (kc0 >= Sk) return;
  bf16x4 o = {};
  if (jc < Nc1) {
    const float* row = jac2 + (size_t)inv1[jc] * 4096;
    #pragma unroll
    for (int e = 0; e < 4; ++e)
      o[e] = (kc0 + e < Nc2) ? (bf16)row[inv2[kc0 + e]] : (bf16)0.f;
  }
  *(bf16x4*)(dst + (size_t)jc * Sk + kc0) = o;
}

// W3c[o][kc] = W3[o][inv2[kc]]  (kc<Nc2 else 0), stride Sk
__global__ __launch_bounds__(256) void g_W3c(const float* __restrict__ W3,
    const int* __restrict__ inv2, const int* __restrict__ meta,
    bf16* __restrict__ dst) {
  const int Sk = meta[1], Nc2 = meta[5];
  const int kc0 = blockIdx.x * 1024 + threadIdx.x * 4;
  if (kc0 >= Sk) return;
  const float* row = W3 + (size_t)blockIdx.y * 4096;
  bf16x4 o;
  #pragma unroll
  for (int e = 0; e < 4; ++e)
    o[e] = (kc0 + e < Nc2) ? (bf16)row[inv2[kc0 + e]] : (bf16)0.f;
  *(bf16x4*)(dst + (size_t)blockIdx.y * Sk + kc0) = o;
}

// ---------------- bf16 NT GEMM, m97 structure, runtime N/K from meta --------
// C[m][n] = sum_k A[m][k]*B[n][k]; strides: A,B rows = K, C rows = N.
__device__ inline void load_lds16(const bf16* g, bf16* lds) {
  __builtin_amdgcn_global_load_lds(
      (const __attribute__((address_space(1))) void*)g,
      (__attribute__((address_space(3))) void*)lds, 16, 0, 0);
}

template <typename CT>
__global__ __launch_bounds__(256) void gemm_nt_m(const bf16* __restrict__ A,
    const bf16* __restrict__ B, CT* __restrict__ C,
    const int* __restrict__ meta, int nIdx, int kIdx) {
  const int N = meta[nIdx], K = meta[kIdx];
  constexpr int BM = 128, BN = 128, BK = 32;
  const int tm = blockIdx.y, tn = blockIdx.x;
  if (tn * BN >= N) return;                           // compacted-N early exit
  __shared__ __align__(16) bf16 As[BM * BK];
  __shared__ __align__(16) bf16 Bs[BN * BK];
  const int tid = threadIdx.x, lane = tid & 63, wave = tid >> 6;
  const int wm = wave >> 1, wn = wave & 1;            // 2x2 waves, 64x64 each

  f32x4 acc[4][4] = {};

  const int ldrow = lane >> 2;          // row within 16-row staging chunk
  const int ldk   = (lane & 3) * 8;     // k offset (bf16 elements)
  const long arow0 = (long)(tm * BM) * K;
  const long brow0 = (long)(tn * BN) * K;

  for (int kt = 0; kt < K; kt += BK) {
    #pragma unroll
    for (int s = 0; s < 2; ++s) {
      const int chunk = wave * 2 + s;                 // 8 chunks of 16 rows
      const int row = chunk * 16 + ldrow;
      load_lds16(A + arow0 + (long)row * K + kt + ldk, As + chunk * 512);
      load_lds16(B + brow0 + (long)row * K + kt + ldk, Bs + chunk * 512);
    }
    __syncthreads();
    bf16x8 af[4], bfr[4];
    const int ko = (lane >> 4) * 8;
    const int fr = lane & 15;
    #pragma unroll
    for (int f = 0; f < 4; ++f) {
      af[f]  = *(const bf16x8*)(As + (wm * 64 + f * 16 + fr) * BK + ko);
      bfr[f] = *(const bf16x8*)(Bs + (wn * 64 + f * 16 + fr) * BK + ko);
    }
    #pragma unroll
    for (int mf = 0; mf < 4; ++mf)
      #pragma unroll
      for (int nf = 0; nf < 4; ++nf)
        acc[mf][nf] = __builtin_amdgcn_mfma_f32_16x16x32_bf16(
            af[mf], bfr[nf], acc[mf][nf], 0, 0, 0);
    __syncthreads();
  }

  // epilogue: C/D layout col=lane&15, row=(lane>>4)*4+reg (m89/m91 verified)
  const int cr = (lane >> 4) * 4;
  const int cc = lane & 15;
  #pragma unroll
  for (int mf = 0; mf < 4; ++mf) {
    const int r0 = tm * BM + wm * 64 + mf * 16 + cr;
    #pragma unroll
    for (int nf = 0; nf < 4; ++nf) {
      const long c0 = (long)r0 * N + tn * BN + wn * 64 + nf * 16 + cc;
      #pragma unroll
      for (int r = 0; r < 4; ++r)
        C[c0 + (long)r * N] = (CT)acc[mf][nf][r];
    }
  }
}

// ---------------------------------------------------------------------------
extern "C" void kernel_launch(void* const* d_in, const int* in_sizes, int n_in,
                              void* d_out, int out_size, void* d_ws, size_t ws_size,
                              hipStream_t stream) {
  const float* x  = (const float*)d_in[0];
  const float* W1 = (const float*)d_in[1];   // [4096][2048]
  const float* W2 = (const float*)d_in[2];   // [4096][4096]
  const float* W3 = (const float*)d_in[3];   // [2048][4096]
  float* out = (float*)d_out;
  constexpr int IN = 2048, HS = 4096, ON = 2048;

  // output layout (flat concat in return order)
  float* z3   = out;                            // [1][2048]
  float* DJM  = z3 + IN;                        // [2048][2048]  (i,o)
  float* jac0 = DJM + (size_t)IN * ON;          // W1^T [2048][4096]
  float* jac1 = jac0 + (size_t)IN * HS;         // diag(m1) [4096][4096]
  float* jac2 = jac1 + (size_t)HS * HS;         // W2^T [4096][4096]
  float* jac3 = jac2 + (size_t)HS * HS;         // diag(m2) [4096][4096]
  float* jac4 = jac3 + (size_t)HS * HS;         // W3^T [4096][2048]
  float* jac5 = jac4 + (size_t)HS * ON;         // eye [2048][2048]

  // workspace (≈81 MB of ws used)
  char* ws = (char*)d_ws;
  float* h1 = (float*)ws;                       // [4096]
  float* m1 = h1 + HS;
  float* h2 = m1 + HS;
  float* m2 = h2 + HS;
  int* meta = (int*)(ws + (64 << 10));          // 6 ints
  int* inv1 = (int*)(ws + (128 << 10));         // [4096]
  int* inv2 = (int*)(ws + (192 << 10));         // [4096]
  size_t off = 1 << 20;
  bf16* W1c = (bf16*)(ws + off); off += (size_t)IN * HS * 2;  // [2048][Sj]
  bf16* W2c = (bf16*)(ws + off); off += (size_t)HS * HS * 2;  // [Sj][Sk]
  bf16* W3c = (bf16*)(ws + off); off += (size_t)ON * HS * 2;  // [2048][Sk]
  bf16* T1c = (bf16*)(ws + off);                              // [2048][Sj]

  // 1) forward matvecs (f32 exact)
  mv_relu<<<HS * 64 / 256, 256, 0, stream>>>(W1, x,  h1, m1, nullptr, IN);
  mv_relu<<<HS * 64 / 256, 256, 0, stream>>>(W2, h1, h2, m2, nullptr, HS);
  mv_relu<<<ON * 64 / 256, 256, 0, stream>>>(W3, h2, nullptr, nullptr, z3, HS);

  // 2) mask scan -> compaction indices + runtime sizes
  scan_meta<<<1, 1024, 0, stream>>>(m1, m2, meta, inv1, inv2);

  // 3) f32 transposed jacobian outputs (float4 both sides)
  transpose_f32<<<dim3(IN / 32, HS / 32), 256, 0, stream>>>(W1, jac0, HS, IN);
  transpose_f32<<<dim3(HS / 32, HS / 32), 256, 0, stream>>>(W2, jac2, HS, HS);
  transpose_f32<<<dim3(HS / 32, ON / 32), 256, 0, stream>>>(W3, jac4, ON, HS);

  // 4) diagonal jacobians + identity
  diag_fill<<<((size_t)HS * HS / 4) / 256, 256, 0, stream>>>(jac1, m1, HS);
  diag_fill<<<((size_t)HS * HS / 4) / 256, 256, 0, stream>>>(jac3, m2, HS);
  diag_fill<<<((size_t)ON * ON / 4) / 256, 256, 0, stream>>>(jac5, nullptr, ON);

  // 5) compacted bf16 GEMM operands (exact: dropped columns are exact zeros)
  g_W1c<<<dim3(4, IN), 256, 0, stream>>>(jac0, inv1, meta, W1c);
  g_W2c<<<dim3(4, HS), 256, 0, stream>>>(jac2, inv1, inv2, meta, W2c);
  g_W3c<<<dim3(4, ON), 256, 0, stream>>>(W3, inv2, meta, W3c);

  // 6) DJM = (W1^T D1)(W2^T D2 W3^T), ReLU-compacted:
  //    T1c[o][jc] = sum_kc W3c[o][kc] * W2c[jc][kc]   (M=2048, N=Sj, K=Sk)
  gemm_nt_m<bf16><<<dim3(HS / 128, ON / 128), 256, 0, stream>>>(W3c, W2c, T1c, meta, 0, 1);
  //    DJM[i][o]  = sum_jc W1c[i][jc] * T1c[o][jc]    (M=2048, N=2048, K=Sj)
  gemm_nt_m<float><<<dim3(ON / 128, IN / 128), 256, 0, stream>>>(W1c, T1c, DJM, meta, 2, 3);
}